// Round 8
// baseline (226.510 us; speedup 1.0000x reference)
//
#include <hip/hip_runtime.h>

// SNN forward: [prep: X->bits + W splits] -> [GEMM1+scan1: A expanded from
// bit-words in VGPRs (X is binary!), B-only ring-3 LDS, counted vmcnt,
// 512 thr / 8 waves, ballot bit-packed spike out] -> [FUSED GEMM2+scan2:
// 64 blocks, 8 waves, bit-A, wave-private B ring, zero K-loop barriers,
// yc in LDS, in-kernel scan, direct Out write].
// f16 split-2: W = hi + lo (both f16), residual ~2^-24 => fp32-grade MFMA.
// R8 = R7 resubmit: container-level infra failure, no measurement; source
// re-audited (vmcnt ledgers, barrier uniformity, LDS budgets, bit layouts).
// R7 ledger: gemm1 67us invariant across 4 structures = 500 TF = the
// 128^2/2-barrier structural ceiling; per-CU phase: LDS reads 1540 cyc vs
// MFMA 1242 -> halve LDS traffic via A-from-bits (X is Bernoulli 0/1).
// rest 122us invariant across 4 gemm2 structures -> fuse layer 2 entirely,
// kill y2 roundtrip + 1 launch, decompose the residual.

#define NN 64
#define II 256
#define HH 1024
#define OO 18
#define TT 500
#define TTP 512   // padded t stride for Xbits rows

#define D_SR 0.9048374180359595f   // exp(-1/10)
#define C_SR 0.27182818284590454f  // e/10
#define D_RF 0.36787944117144233f  // exp(-1)
#define C_RF 2.718281828459045f    // e
#define THETA 10.0f
#define REFS (-20.0f)

typedef _Float16 f16;
typedef _Float16 f16x8 __attribute__((ext_vector_type(8)));
typedef float f32x4 __attribute__((ext_vector_type(4)));
typedef unsigned int uint;
typedef unsigned long long u64;

__device__ __forceinline__ void gl2lds16(const void* g, void* l) {
    __builtin_amdgcn_global_load_lds(
        (const __attribute__((address_space(1))) void*)g,
        (__attribute__((address_space(3))) void*)l, 16, 0, 0);
}

// 8 bits -> 8 f16 {0,1}: 2 bits per u32 word of the f16x8
__device__ __forceinline__ f16x8 expand8(uint by) {
    union { f16x8 v; uint u[4]; } A;
#pragma unroll
    for (int e = 0; e < 4; ++e) {
        uint b0 = (by >> (2 * e)) & 1u, b1 = (by >> (2 * e + 1)) & 1u;
        A.u[e] = (b0 ? 0x3C00u : 0u) | (b1 ? 0x3C000000u : 0u);
    }
    return A.v;
}

// ---------------- prep: X -> bit rows (ballot) + W1 hi/lo + W2 hi/lo -------
// grid 3200: [0,2048) X tiles, [2048,3072) W1, [3072,3200) W2.
// Xbits[n][t] = 32 B: u32 word j, bit m  <->  X[n][i = j*32+m][t] != 0.
__launch_bounds__(256)
__global__ void prep_all(const float* __restrict__ X, const float* __restrict__ W1,
                         const float* __restrict__ W2, u64* __restrict__ Xb,
                         f16* __restrict__ W1h, f16* __restrict__ W1l,
                         f16* __restrict__ W2h, f16* __restrict__ W2l) {
    __shared__ float tile[64][65];
    const int b = blockIdx.x;
    const int tid = threadIdx.x;

    if (b < 2048) {
        const int t0 = (b & 7) * 64, i0 = ((b >> 3) & 3) * 64, n = b >> 5;
        const int tx = tid & 63, q = tid >> 6;
        const float* Xn = X + (size_t)n * II * TT;
#pragma unroll 4
        for (int j = 0; j < 16; ++j) {
            int il = j * 4 + q;
            int t = t0 + tx;
            tile[il][tx] = (t < TT) ? Xn[(size_t)(i0 + il) * TT + t] : 0.f;
        }
        __syncthreads();
        const int wv = tid >> 6, ln = tid & 63;
        const int widx = (b >> 3) & 3;   // u64 word = i0/64
#pragma unroll
        for (int tt = 0; tt < 16; ++tt) {
            int t = wv * 16 + tt;
            u64 m = __ballot(tile[ln][t] != 0.0f);   // bit ln <-> i0+ln
            if (ln == 0 && (t0 + t) < TT)
                Xb[((size_t)n * TTP + t0 + t) * 4 + widx] = m;
        }
    } else if (b < 3072) {
        int idx = (b - 2048) * 256 + tid;
        float w = W1[idx];
        f16 h = (f16)w;
        f16 l = (f16)(w - (float)h);
        W1h[idx] = h;
        W1l[idx] = l;
    } else {
        int idx = (b - 3072) * 256 + tid;
        int o = idx >> 10;
        float w = (o < OO) ? W2[idx] : 0.f;
        f16 h = (f16)w;
        f16 l = (f16)(w - (float)h);
        W2h[idx] = h;
        W2l[idx] = l;
    }
}

// ---------------- FUSED layer 1: A-from-bits, B ring-3, 8 waves -------------
// grid (8, 64), 512 thr. Per block: 4 t-chunks of 128.
// A: per chunk, lane holds 4 rows' bit-bytes (byte kq of 8 words, packed
// into 8 u32). B: ring-3 Bh+Bl slots (16 KB each), swizzled src+read.
__launch_bounds__(512, 4)
__global__ void gemm1_scan1(const uint* __restrict__ Xb32, const f16* __restrict__ Wh,
                            const f16* __restrict__ Wl, u64* __restrict__ Sb) {
    __shared__ __align__(16) char smem[67584];  // ring 3x16384 aliased under yb
    float* yb = (float*)smem;

    const int tid = threadIdx.x;
    const int wave = tid >> 6, lane = tid & 63;

    // XCD swizzle: the 8 h-tiles of one n share an XCD
    const int f = blockIdx.y * 8 + blockIdx.x;
    const int x = f & 7, g = f >> 3;
    const int n = x * 8 + (g & 7);
    const int ht = g >> 3;
    const int h0g = ht * 128;

    const int rbl = wave * 16 + (lane >> 2);   // staged B row 0..127
    const int koff = (((lane & 3) ^ ((lane >> 3) & 3))) * 8;  // swizzled src slot
    const f16* gBh0 = Wh + (size_t)(h0g + rbl) * II + koff;
    const f16* gBl0 = Wl + (size_t)(h0g + rbl) * II + koff;

    const int wm = wave & 1, wn = wave >> 1;   // 2m x 4n
    const int fr = lane & 15, kq = lane >> 4;
    const int kz = (kq ^ ((fr >> 1) & 3)) * 8;  // swizzled read slot (f16 idx)
    const int sh = kq * 8;

    float p1 = 0.f, a1 = 0.f, p2 = 0.f, a2 = 0.f;  // scan state (tid<128)

    for (int c = 0; c < 4; ++c) {
        const int t0 = c * 128;
        const int TCe = (TT - t0 < 128) ? (TT - t0) : 128;

        // A bit-rows: 4 rows x 8 u32 words; keep byte kq of each word,
        // packed 4-per-u32 -> xb[i*2 + (kk>=4)]
        uint xb[8];
#pragma unroll
        for (int i = 0; i < 4; ++i) {
            int r = t0 + wm * 64 + i * 16 + fr;
            if (r > TT - 1) r = TT - 1;
            const uint* xr = Xb32 + ((size_t)n * TTP + r) * 8;
            uint4 wA = *(const uint4*)xr;
            uint4 wB = *(const uint4*)(xr + 4);
            xb[i * 2 + 0] = ((wA.x >> sh) & 0xFFu) | (((wA.y >> sh) & 0xFFu) << 8)
                          | (((wA.z >> sh) & 0xFFu) << 16) | (((wA.w >> sh) & 0xFFu) << 24);
            xb[i * 2 + 1] = ((wB.x >> sh) & 0xFFu) | (((wB.y >> sh) & 0xFFu) << 8)
                          | (((wB.z >> sh) & 0xFFu) << 16) | (((wB.w >> sh) & 0xFFu) << 24);
        }

        auto stage = [&](int kk2, int b) {
            f16* Bh_b = (f16*)(smem + b * 16384);
            const int ko = kk2 * 32;
            gl2lds16(gBh0 + ko, Bh_b + wave * 512);
            gl2lds16(gBl0 + ko, Bh_b + 4096 + wave * 512);
        };
        stage(0, 0);
        stage(1, 1);

        f32x4 acc[4][2] = {};
#pragma unroll
        for (int kk = 0; kk < 8; ++kk) {
            // slot kk's 2 DMAs done when only the newest stage (2) remains
            if (kk < 7) asm volatile("s_waitcnt vmcnt(2)" ::: "memory");
            else        asm volatile("s_waitcnt vmcnt(0)" ::: "memory");
            __builtin_amdgcn_s_barrier();
            __builtin_amdgcn_sched_barrier(0);
            if (kk < 6) stage(kk + 2, (kk + 2) % 3);

            const f16* Bh_b = (const f16*)(smem + (kk % 3) * 16384);
            const f16* Bl_b = Bh_b + 4096;

            f16x8 av[4], bhv[2], blv[2];
#pragma unroll
            for (int i = 0; i < 4; ++i)
                av[i] = expand8((xb[i * 2 + (kk >> 2)] >> ((kk & 3) * 8)) & 0xFFu);
#pragma unroll
            for (int j = 0; j < 2; ++j) {
                bhv[j] = *(const f16x8*)(Bh_b + (wn * 32 + j * 16 + fr) * 32 + kz);
                blv[j] = *(const f16x8*)(Bl_b + (wn * 32 + j * 16 + fr) * 32 + kz);
            }
            __builtin_amdgcn_s_setprio(1);
#pragma unroll
            for (int i = 0; i < 4; ++i)
#pragma unroll
                for (int j = 0; j < 2; ++j) {
                    acc[i][j] = __builtin_amdgcn_mfma_f32_16x16x32_f16(av[i], bhv[j], acc[i][j], 0, 0, 0);
                    acc[i][j] = __builtin_amdgcn_mfma_f32_16x16x32_f16(av[i], blv[j], acc[i][j], 0, 0, 0);
                }
            __builtin_amdgcn_s_setprio(0);
        }
        __syncthreads();  // all frag reads done before epilogue overwrites ring

        // epilogue: acc -> yb (t-major, stride 132)
#pragma unroll
        for (int i = 0; i < 4; ++i)
#pragma unroll
            for (int j = 0; j < 2; ++j) {
                int tr = wm * 64 + i * 16 + kq * 4;
                int hc = wn * 32 + j * 16 + fr;
#pragma unroll
                for (int r = 0; r < 4; ++r)
                    yb[(tr + r) * 132 + hc] = acc[i][j][r];
            }
        __syncthreads();

        // sequential scan (waves 0-1); 8-deep ring; ballot -> bit rows
        if (tid < 128) {
            u64* sq = Sb + ((size_t)n * TT + t0) * 16 + ht * 2 + wave;
            float rb_[8];
#pragma unroll
            for (int j = 0; j < 8; ++j) rb_[j] = yb[j * 132 + tid];
            int t = 0;
            for (; t + 8 <= TCe; t += 8) {
#pragma unroll
                for (int j = 0; j < 8; ++j) {
                    float xv = rb_[j];
                    int tn = t + j + 8;
                    rb_[j] = (tn < TCe) ? yb[tn * 132 + tid] : 0.f;
                    a1 = D_SR * (a1 + p1);
                    p1 = D_SR * p1 + xv;
                    float ut = C_SR * a1;
                    a2 = D_RF * (a2 + p2);
                    float u = ut + C_RF * a2;
                    float s = (u >= THETA) ? 1.0f : 0.0f;
                    p2 = D_RF * p2 + REFS * s;
                    u64 m = __ballot(u >= THETA);
                    if (lane == 0) sq[(size_t)(t + j) * 16] = m;
                }
            }
            int rem = TCe - t;
#pragma unroll
            for (int j = 0; j < 8; ++j) {
                if (j < rem) {   // uniform predicate: all 64 lanes enter
                    float xv = rb_[j];
                    a1 = D_SR * (a1 + p1);
                    p1 = D_SR * p1 + xv;
                    float ut = C_SR * a1;
                    a2 = D_RF * (a2 + p2);
                    float u = ut + C_RF * a2;
                    float s = (u >= THETA) ? 1.0f : 0.0f;
                    p2 = D_RF * p2 + REFS * s;
                    u64 m = __ballot(u >= THETA);
                    if (lane == 0) sq[(size_t)(t + j) * 16] = m;
                }
            }
        }
        __syncthreads();  // yb reads done; next chunk's staging may overwrite
    }
}

// ---------------- FUSED layer 2: bit-A GEMM + scan + out, one block per n --
// grid 64, 512 thr / 8 waves. Wave w owns t in [w*64, w*64+64) (4 m-tiles).
// B: wave-private ring-3 of {Bh,Bl} 4 KB slots (W2 L2-hot; 8x dup free).
// Zero barriers in the K-loop; own-wave counted vmcnt only.
__launch_bounds__(512)
__global__ void gemm2_scan2(const uint* __restrict__ Ab, const f16* __restrict__ W2h,
                            const f16* __restrict__ W2l, float* __restrict__ Out) {
    __shared__ __align__(16) char L[162304];
    // [0, 98304): 8 waves x 3 slots x 4096 B  (sb 36000 aliases after GEMM)
    // [98304, 162304): yc 500x32 f32
    float* yc = (float*)(L + 98304);
    float* sb = (float*)L;

    const int n = blockIdx.x, tid = threadIdx.x;
    const int wave = tid >> 6, lane = tid & 63;
    const int fr = lane & 15, kq = lane >> 4;
    const int sh = kq * 8;
    const int srow = lane >> 2;
    const int koff = (((lane & 3) ^ ((lane >> 3) & 3))) * 8;
    const int kz = (kq ^ ((fr >> 1) & 3)) * 8;

    const f16* gh0 = W2h + (size_t)srow * HH + koff;
    const f16* gh1 = W2h + (size_t)(srow + 16) * HH + koff;
    const f16* gl0 = W2l + (size_t)srow * HH + koff;
    const f16* gl1 = W2l + (size_t)(srow + 16) * HH + koff;

    auto stage = [&](int kk2, int b) {
        char* s = L + (wave * 3 + b) * 4096;
        const int ko = kk2 * 32;
        gl2lds16(gh0 + ko, s);
        gl2lds16(gh1 + ko, s + 1024);
        gl2lds16(gl0 + ko, s + 2048);
        gl2lds16(gl1 + ko, s + 3072);
    };

    // A bit-row pointers (4 m-tiles per wave; t = wave*64 + mi*16 + fr)
    const uint* ar[4];
#pragma unroll
    for (int mi = 0; mi < 4; ++mi) {
        int t = wave * 64 + mi * 16 + fr;
        if (t > TT - 1) t = TT - 1;
        ar[mi] = Ab + (size_t)(n * TT + t) * 32;
    }

    uint ac[4], an[4];
#pragma unroll
    for (int mi = 0; mi < 4; ++mi) ac[mi] = ar[mi][0];   // A(0) before stages
    stage(0, 0);
    stage(1, 1);

    f32x4 acc[4][2] = {};
#pragma unroll
    for (int kk = 0; kk < 32; ++kk) {
        // own-wave: queue = [S(kk)<=4, A(kk) 4, S(kk+1) 4]; vmcnt(4)
        // retires S(kk)+A(kk) (in-order), leaves S(kk+1) in flight.
        if (kk < 31) asm volatile("s_waitcnt vmcnt(4)" ::: "memory");
        else         asm volatile("s_waitcnt vmcnt(0)" ::: "memory");
        __builtin_amdgcn_sched_barrier(0);
        if (kk < 31) {
#pragma unroll
            for (int mi = 0; mi < 4; ++mi) an[mi] = ar[mi][kk + 1];
        }
        if (kk < 30) stage(kk + 2, (kk + 2) % 3);

        const f16* Bh_b = (const f16*)(L + (wave * 3 + kk % 3) * 4096);
        const f16* Bl_b = Bh_b + 1024;

        f16x8 bh[2], bl[2];
#pragma unroll
        for (int j = 0; j < 2; ++j) {
            bh[j] = *(const f16x8*)(Bh_b + (j * 16 + fr) * 32 + kz);
            bl[j] = *(const f16x8*)(Bl_b + (j * 16 + fr) * 32 + kz);
        }
        __builtin_amdgcn_s_setprio(1);
#pragma unroll
        for (int mi = 0; mi < 4; ++mi) {
            f16x8 a = expand8((ac[mi] >> sh) & 0xFFu);
#pragma unroll
            for (int j = 0; j < 2; ++j) {
                acc[mi][j] = __builtin_amdgcn_mfma_f32_16x16x32_f16(a, bh[j], acc[mi][j], 0, 0, 0);
                acc[mi][j] = __builtin_amdgcn_mfma_f32_16x16x32_f16(a, bl[j], acc[mi][j], 0, 0, 0);
            }
        }
        __builtin_amdgcn_s_setprio(0);
#pragma unroll
        for (int mi = 0; mi < 4; ++mi) ac[mi] = an[mi];
    }

    // epilogue: acc -> yc (t-major, stride 32)
#pragma unroll
    for (int mi = 0; mi < 4; ++mi)
#pragma unroll
        for (int j = 0; j < 2; ++j) {
            int tb = wave * 64 + mi * 16 + kq * 4;
            int oc = j * 16 + fr;
#pragma unroll
            for (int r = 0; r < 4; ++r)
                if (tb + r < TT) yc[(tb + r) * 32 + oc] = acc[mi][j][r];
        }
    __syncthreads();

    // scan (tid<32): 500 steps, 8-deep ring; spikes -> sb
    if (tid < 32) {
        float p1 = 0.f, a1 = 0.f, p2 = 0.f, a2 = 0.f;
        float rb_[8];
#pragma unroll
        for (int j = 0; j < 8; ++j) rb_[j] = yc[j * 32 + tid];
        int t = 0;
        for (; t + 8 <= TT; t += 8) {
#pragma unroll
            for (int j = 0; j < 8; ++j) {
                float xv = rb_[j];
                int tn = t + j + 8;
                rb_[j] = (tn < TT) ? yc[tn * 32 + tid] : 0.f;
                a1 = D_SR * (a1 + p1);
                p1 = D_SR * p1 + xv;
                float ut = C_SR * a1;
                a2 = D_RF * (a2 + p2);
                float u = ut + C_RF * a2;
                float s = (u >= THETA) ? 1.0f : 0.0f;
                p2 = D_RF * p2 + REFS * s;
                if (tid < OO) sb[tid * TT + t + j] = s;
            }
        }
#pragma unroll
        for (int j = 0; j < 8; ++j) {
            if (t + j < TT) {
                float xv = rb_[j];
                a1 = D_SR * (a1 + p1);
                p1 = D_SR * p1 + xv;
                float ut = C_SR * a1;
                a2 = D_RF * (a2 + p2);
                float u = ut + C_RF * a2;
                float s = (u >= THETA) ? 1.0f : 0.0f;
                p2 = D_RF * p2 + REFS * s;
                if (tid < OO) sb[tid * TT + t + j] = s;
            }
        }
    }
    __syncthreads();

    float* on = Out + (size_t)n * OO * TT;
    for (int e = tid; e < OO * TT; e += 512) on[e] = sb[e];
}

extern "C" void kernel_launch(void* const* d_in, const int* in_sizes, int n_in,
                              void* d_out, int out_size, void* d_ws, size_t ws_size,
                              hipStream_t stream) {
    const float* X  = (const float*)d_in[0];
    const float* W1 = (const float*)d_in[1];
    const float* W2 = (const float*)d_in[2];
    float* out = (float*)d_out;

    const size_t s_sb = (size_t)NN * TT * 16 * 8;   //  4,096,000 (spike bits)
    const size_t s_Xb = (size_t)NN * TTP * 32;      //  1,048,576 (input bits)
    const size_t s_W  = (size_t)HH * II * 2;        //    524,288 (x2)
    const size_t s_W2 = (size_t)32 * HH * 2;        //     65,536 (x2)
    // total ~6.3 MB

    char* w = (char*)d_ws;
    u64*   sbb = (u64*)w;  w += s_sb;
    u64*   Xbt = (u64*)w;  w += s_Xb;
    f16*   W1h = (f16*)w;  w += s_W;
    f16*   W1l = (f16*)w;  w += s_W;
    f16*   W2h = (f16*)w;  w += s_W2;
    f16*   W2l = (f16*)w;  w += s_W2;

    prep_all<<<3200, 256, 0, stream>>>(X, W1, W2, Xbt, W1h, W1l, W2h, W2l);

    gemm1_scan1<<<dim3(8, NN), 512, 0, stream>>>((const uint*)Xbt, W1h, W1l, sbb);

    gemm2_scan2<<<NN, 512, 0, stream>>>((const uint*)sbb, W2h, W2l, out);
}